// Round 1
// baseline (354.377 us; speedup 1.0000x reference)
//
#include <hip/hip_runtime.h>
#include <hip/hip_bf16.h>
#include <stdint.h>

typedef __attribute__((ext_vector_type(8))) short s16x8;
typedef __attribute__((ext_vector_type(4))) float f32x4;

#define D_MODEL 1024
#define D_INNER 2048
#define DT_RANK 64
#define NSTATE 16
#define BATCH 2
#define SEQ 2048
#define MROWS (BATCH*SEQ)   // 4096
#define NC 32
#define CLEN (SEQ/NC)       // 64

__device__ __forceinline__ float fsigmoid(float v) { return 1.f / (1.f + __expf(-v)); }

// ---------- setup: fp32->bf16 conversions + A = -exp(A_log) ----------
__global__ __launch_bounds__(256) void setup_convert(
    const float* __restrict__ x, const float* __restrict__ ipw,
    const float* __restrict__ xpw, const float* __restrict__ dtw,
    const float* __restrict__ opw, const float* __restrict__ alog,
    __hip_bfloat16* __restrict__ xbf, __hip_bfloat16* __restrict__ wbf,
    __hip_bfloat16* __restrict__ xpwbf, __hip_bfloat16* __restrict__ dtwbf,
    __hip_bfloat16* __restrict__ owbf, float* __restrict__ Aneg) {
  int i = blockIdx.x * 256 + threadIdx.x;
  const int n0 = MROWS * D_MODEL;               // x: 4194304
  const int n1 = n0 + 2 * D_INNER * D_MODEL;    // in_proj: +4194304
  const int n2 = n1 + 96 * D_INNER;             // x_proj: +196608
  const int n3 = n2 + D_INNER * DT_RANK;        // dt_proj: +131072
  const int n4 = n3 + D_MODEL * D_INNER;        // out_proj: +2097152
  const int n5 = n4 + D_INNER * NSTATE;         // A_log: +32768
  if (i < n0) { xbf[i] = __float2bfloat16(x[i]); return; }
  if (i < n1) { int j = i - n0; wbf[j] = __float2bfloat16(ipw[j]); return; }
  if (i < n2) { int j = i - n1; xpwbf[j] = __float2bfloat16(xpw[j]); return; }
  if (i < n3) { int j = i - n2; dtwbf[j] = __float2bfloat16(dtw[j]); return; }
  if (i < n4) { int j = i - n3; owbf[j] = __float2bfloat16(opw[j]); return; }
  if (i < n5) { int j = i - n4; Aneg[j] = -expf(alog[j]); return; }
}

// ---------- generic bf16 MFMA GEMM: C[M,N] = A[M,K] * Bw[N,K]^T ----------
// 128x128 tile, BK=32, 4 waves in 2x2, each wave 64x64 (4x4 frags of 16x16x32).
// MODE 0: GEMM1 (in_proj): col<2048 -> xs fp32 ; col>=2048 -> silu -> zsil bf16
// MODE 1: GEMM2 (x_proj):  col<64 -> dtr bf16 ; 64<=col<96 -> bc fp32
// MODE 2: GEMM3 (dt_proj): +bias, softplus -> dt fp32
// MODE 3: GEMM4 (out_proj): plain fp32 store
template<int MODE>
__global__ __launch_bounds__(256)
void gemm_bt(const __hip_bfloat16* __restrict__ A,
             const __hip_bfloat16* __restrict__ Bw,
             int M, int N, int K,
             float* __restrict__ e0,
             __hip_bfloat16* __restrict__ eb0,
             const float* __restrict__ bias) {
  __shared__ alignas(16) unsigned short As[128][40];  // +8 pad: rows 80B (16B-aligned), spreads banks
  __shared__ alignas(16) unsigned short Bs[128][40];
  const int m0 = blockIdx.x * 128;
  const int n0 = blockIdx.y * 128;
  const int tid = threadIdx.x;
  const int lane = tid & 63;
  const int wave = tid >> 6;
  const int wr = wave >> 1, wc = wave & 1;
  const int lrow = lane & 15;
  const int kh = lane >> 4;  // 0..3 -> k offset kh*8

  f32x4 acc[4][4] = {};

  for (int k0 = 0; k0 < K; k0 += 32) {
#pragma unroll
    for (int it = 0; it < 2; ++it) {
      int c = tid + it * 256;        // 512 chunks of 8 bf16
      int row = c >> 2, kc = c & 3;
      s16x8 va = *(const s16x8*)(A + (size_t)(m0 + row) * K + k0 + kc * 8);
      *(s16x8*)(&As[row][kc * 8]) = va;
      int brow = n0 + row;
      s16x8 vb = {0, 0, 0, 0, 0, 0, 0, 0};
      if (brow < N) vb = *(const s16x8*)(Bw + (size_t)brow * K + k0 + kc * 8);
      *(s16x8*)(&Bs[row][kc * 8]) = vb;
    }
    __syncthreads();
    s16x8 af[4], bfr[4];
#pragma unroll
    for (int f = 0; f < 4; ++f) af[f] = *(const s16x8*)(&As[wr * 64 + f * 16 + lrow][kh * 8]);
#pragma unroll
    for (int g = 0; g < 4; ++g) bfr[g] = *(const s16x8*)(&Bs[wc * 64 + g * 16 + lrow][kh * 8]);
#pragma unroll
    for (int f = 0; f < 4; ++f)
#pragma unroll
      for (int g = 0; g < 4; ++g)
        acc[f][g] = __builtin_amdgcn_mfma_f32_16x16x32_bf16(af[f], bfr[g], acc[f][g], 0, 0, 0);
    __syncthreads();
  }

  // epilogue: lane holds D[row=(lane>>4)*4+j][col=lane&15] per frag (m89-verified)
#pragma unroll
  for (int f = 0; f < 4; ++f) {
    const int rbase = m0 + wr * 64 + f * 16 + (lane >> 4) * 4;
#pragma unroll
    for (int g = 0; g < 4; ++g) {
      const int col = n0 + wc * 64 + g * 16 + (lane & 15);
#pragma unroll
      for (int j = 0; j < 4; ++j) {
        float v = acc[f][g][j];
        const int r = rbase + j;
        if (MODE == 0) {
          if (col < D_INNER) e0[(size_t)r * D_INNER + col] = v;
          else {
            float s = v * fsigmoid(v);
            eb0[(size_t)r * D_INNER + (col - D_INNER)] = __float2bfloat16(s);
          }
        } else if (MODE == 1) {
          if (col < DT_RANK) eb0[(size_t)r * DT_RANK + col] = __float2bfloat16(v);
          else if (col < DT_RANK + 2 * NSTATE) e0[(size_t)r * 32 + (col - DT_RANK)] = v;
        } else if (MODE == 2) {
          float t = v + bias[col];
          float sp = (t > 20.f) ? t : __logf(1.f + __expf(t));
          e0[(size_t)r * D_INNER + col] = sp;
        } else {
          e0[(size_t)r * D_MODEL + col] = v;
        }
      }
    }
  }
}

// ---------- depthwise causal conv (k=4) + bias + silu ----------
__global__ __launch_bounds__(256)
void conv_silu(const float* __restrict__ xs, const float* __restrict__ cw,
               const float* __restrict__ cb, float* __restrict__ xsc,
               __hip_bfloat16* __restrict__ xscbf) {
  int idx = blockIdx.x * 256 + threadIdx.x;  // B*SEQ*D_INNER = 8388608
  int d = idx & (D_INNER - 1);
  int l = (idx >> 11) & (SEQ - 1);
  float w0 = cw[d * 4 + 0], w1 = cw[d * 4 + 1], w2 = cw[d * 4 + 2], w3 = cw[d * 4 + 3];
  const float* p = xs + (size_t)idx;
  float acc = cb[d];
  if (l >= 3) acc += p[-3 * D_INNER] * w0;
  if (l >= 2) acc += p[-2 * D_INNER] * w1;
  if (l >= 1) acc += p[-1 * D_INNER] * w2;
  acc += p[0] * w3;
  float s = acc * fsigmoid(acc);
  xsc[idx] = s;
  xscbf[idx] = __float2bfloat16(s);
}

// ---------- scan pass 1: per-chunk final state + decay product (h0=0) ----------
__global__ __launch_bounds__(256)
void scan_pass1(const float* __restrict__ dt, const float* __restrict__ xsc,
                const float* __restrict__ bc, const float* __restrict__ Aneg,
                float* __restrict__ hfin, float* __restrict__ Pbuf) {
  const int b = blockIdx.z, c = blockIdx.y;
  const int d = blockIdx.x * 256 + threadIdx.x;
  __shared__ float BC[CLEN][32];
  const size_t mrow0 = (size_t)b * SEQ + (size_t)c * CLEN;
  for (int t = threadIdx.x; t < CLEN * 32; t += 256) {
    int i = t >> 5, col = t & 31;
    BC[i][col] = bc[(mrow0 + i) * 32 + col];
  }
  __syncthreads();
  float Ar[16];
#pragma unroll
  for (int n = 0; n < 16; ++n) Ar[n] = Aneg[d * 16 + n];
  float h[16], P[16];
#pragma unroll
  for (int n = 0; n < 16; ++n) { h[n] = 0.f; P[n] = 1.f; }
  size_t base = mrow0 * D_INNER + d;
  for (int l = 0; l < CLEN; ++l) {
    float dtv = dt[base + (size_t)l * D_INNER];
    float u = dtv * xsc[base + (size_t)l * D_INNER];
#pragma unroll
    for (int n = 0; n < 16; ++n) {
      float a = __expf(dtv * Ar[n]);
      h[n] = h[n] * a + u * BC[l][n];
      P[n] *= a;
    }
  }
  size_t o = (((size_t)b * NC + c) * D_INNER + d) * 16;
#pragma unroll
  for (int n = 0; n < 16; ++n) { hfin[o + n] = h[n]; Pbuf[o + n] = P[n]; }
}

// ---------- scan pass 2: cross-chunk combine; hfin becomes h_init per chunk ----------
__global__ __launch_bounds__(256)
void scan_pass2(float* __restrict__ hfin, const float* __restrict__ Pbuf) {
  int idx = blockIdx.x * 256 + threadIdx.x;  // B*D_INNER*16 = 65536
  int b = idx >> 15;
  int dn = idx & 32767;
  float h0 = 0.f;
  for (int c = 0; c < NC; ++c) {
    size_t o = ((size_t)b * NC + c) * 32768 + dn;
    float hf = hfin[o], p = Pbuf[o];
    hfin[o] = h0;
    h0 = hf + p * h0;
  }
}

// ---------- scan pass 3: re-run chunk from h_init, emit y=(scan+xs*D)*silu(z) as bf16 ----------
__global__ __launch_bounds__(256)
void scan_pass3(const float* __restrict__ dt, const float* __restrict__ xsc,
                const float* __restrict__ bc, const float* __restrict__ Aneg,
                const float* __restrict__ hinit, const float* __restrict__ Dv,
                const __hip_bfloat16* __restrict__ zsil,
                __hip_bfloat16* __restrict__ ybf) {
  const int b = blockIdx.z, c = blockIdx.y;
  const int d = blockIdx.x * 256 + threadIdx.x;
  __shared__ float BC[CLEN][32];
  const size_t mrow0 = (size_t)b * SEQ + (size_t)c * CLEN;
  for (int t = threadIdx.x; t < CLEN * 32; t += 256) {
    int i = t >> 5, col = t & 31;
    BC[i][col] = bc[(mrow0 + i) * 32 + col];
  }
  __syncthreads();
  float Ar[16];
#pragma unroll
  for (int n = 0; n < 16; ++n) Ar[n] = Aneg[d * 16 + n];
  float h[16];
  size_t o = (((size_t)b * NC + c) * D_INNER + d) * 16;
#pragma unroll
  for (int n = 0; n < 16; ++n) h[n] = hinit[o + n];
  const float dval = Dv[d];
  size_t base = mrow0 * D_INNER + d;
  for (int l = 0; l < CLEN; ++l) {
    float dtv = dt[base + (size_t)l * D_INNER];
    float xv = xsc[base + (size_t)l * D_INNER];
    float u = dtv * xv;
    float y = 0.f;
#pragma unroll
    for (int n = 0; n < 16; ++n) {
      float a = __expf(dtv * Ar[n]);
      h[n] = h[n] * a + u * BC[l][n];
      y += h[n] * BC[l][16 + n];
    }
    float yo = y + xv * dval;
    float zg = __bfloat162float(zsil[base + (size_t)l * D_INNER]);
    ybf[base + (size_t)l * D_INNER] = __float2bfloat16(yo * zg);
  }
}

extern "C" void kernel_launch(void* const* d_in, const int* in_sizes, int n_in,
                              void* d_out, int out_size, void* d_ws, size_t ws_size,
                              hipStream_t stream) {
  const float* x    = (const float*)d_in[0];
  const float* ipw  = (const float*)d_in[1];
  const float* cw   = (const float*)d_in[2];
  const float* cb   = (const float*)d_in[3];
  const float* xpw  = (const float*)d_in[4];
  const float* dtw  = (const float*)d_in[5];
  const float* dtb  = (const float*)d_in[6];
  const float* alog = (const float*)d_in[7];
  const float* Dv   = (const float*)d_in[8];
  const float* opw  = (const float*)d_in[9];
  float* out = (float*)d_out;

  char* w = (char*)d_ws;
  // layout (bytes); ybf aliases xbf+wbf (dead after GEMM1); dt aliases xs (dead after conv)
  __hip_bfloat16* xbf   = (__hip_bfloat16*)(w + 0);          //  8,388,608
  __hip_bfloat16* wbf   = (__hip_bfloat16*)(w + 8388608);    //  8,388,608
  __hip_bfloat16* ybf   = (__hip_bfloat16*)(w + 0);          // 16,777,216 (alias)
  __hip_bfloat16* owbf  = (__hip_bfloat16*)(w + 16777216);   //  4,194,304
  __hip_bfloat16* xpwbf = (__hip_bfloat16*)(w + 20971520);   //    393,216
  __hip_bfloat16* dtwbf = (__hip_bfloat16*)(w + 21364736);   //    262,144
  float* Aneg           = (float*)(w + 21626880);            //    131,072
  float* xs             = (float*)(w + 21757952);            // 33,554,432
  float* dtbuf          = (float*)(w + 21757952);            // (alias of xs)
  __hip_bfloat16* zsil  = (__hip_bfloat16*)(w + 55312384);   // 16,777,216
  float* xsc            = (float*)(w + 72089600);            // 33,554,432
  __hip_bfloat16* xscbf = (__hip_bfloat16*)(w + 105644032);  // 16,777,216
  __hip_bfloat16* dtrbf = (__hip_bfloat16*)(w + 122421248);  //    524,288
  float* bc             = (float*)(w + 122945536);           //    524,288
  float* hfin           = (float*)(w + 123469824);           //  8,388,608
  float* Pbuf           = (float*)(w + 131858432);           //  8,388,608
  // total: 140,247,040 bytes

  // 1. convert inputs to bf16 (+ A = -exp(A_log))
  {
    const int total = MROWS * D_MODEL + 2 * D_INNER * D_MODEL + 96 * D_INNER +
                      D_INNER * DT_RANK + D_MODEL * D_INNER + D_INNER * NSTATE;
    setup_convert<<<(total + 255) / 256, 256, 0, stream>>>(
        x, ipw, xpw, dtw, opw, alog, xbf, wbf, xpwbf, dtwbf, owbf, Aneg);
  }
  // 2. GEMM1: xz = x @ in_proj^T  -> xs fp32, silu(z) bf16
  gemm_bt<0><<<dim3(32, 32), 256, 0, stream>>>(xbf, wbf, MROWS, 2 * D_INNER, D_MODEL,
                                               xs, zsil, nullptr);
  // 3. depthwise conv + silu -> xsc fp32 + bf16
  conv_silu<<<(MROWS * D_INNER) / 256, 256, 0, stream>>>(xs, cw, cb, xsc, xscbf);
  // 4. GEMM2: x_dbl = xsc @ x_proj^T -> dt_r bf16, B/C fp32
  gemm_bt<1><<<dim3(32, 1), 256, 0, stream>>>(xscbf, xpwbf, MROWS, 96, D_INNER,
                                              bc, dtrbf, nullptr);
  // 5. GEMM3: dt = softplus(dt_r @ dt_proj^T + b) -> fp32
  gemm_bt<2><<<dim3(32, 16), 256, 0, stream>>>(dtrbf, dtwbf, MROWS, D_INNER, DT_RANK,
                                               dtbuf, nullptr, dtb);
  // 6-8. chunked selective scan
  scan_pass1<<<dim3(8, NC, 2), 256, 0, stream>>>(dtbuf, xsc, bc, Aneg, hfin, Pbuf);
  scan_pass2<<<256, 256, 0, stream>>>(hfin, Pbuf);
  scan_pass3<<<dim3(8, NC, 2), 256, 0, stream>>>(dtbuf, xsc, bc, Aneg, hfin, Dv, zsil, ybf);
  // 9. GEMM4: out = y @ out_proj^T
  gemm_bt<3><<<dim3(32, 8), 256, 0, stream>>>(ybf, owbf, MROWS, D_MODEL, D_INNER,
                                              out, nullptr, nullptr);
}

// Round 2
// 294.261 us; speedup vs baseline: 1.2043x; 1.2043x over previous
//
#include <hip/hip_runtime.h>
#include <hip/hip_bf16.h>
#include <stdint.h>

typedef __attribute__((ext_vector_type(8))) short s16x8;
typedef __attribute__((ext_vector_type(4))) float f32x4;
typedef __attribute__((ext_vector_type(4))) unsigned short u16x4;

#define D_MODEL 1024
#define D_INNER 2048
#define DT_RANK 64
#define NSTATE 16
#define BATCH 2
#define SEQ 2048
#define MROWS (BATCH*SEQ)   // 4096
#define NC 32
#define CLEN (SEQ/NC)       // 64

__device__ __forceinline__ float fsigmoid(float v) { return 1.f / (1.f + __expf(-v)); }

__device__ __forceinline__ unsigned short f2bf(float f) {
  __hip_bfloat16 h = __float2bfloat16(f);
  return *(unsigned short*)&h;
}

__device__ __forceinline__ void gl_lds16(const void* g, void* l) {
  __builtin_amdgcn_global_load_lds(
      (const __attribute__((address_space(1))) void*)g,
      (__attribute__((address_space(3))) void*)l, 16, 0, 0);
}

// ---------- setup: fp32->bf16 conversions + A = -exp(A_log), 8 elems/thread ----------
__global__ __launch_bounds__(256) void setup_convert(
    const float* __restrict__ x, const float* __restrict__ ipw,
    const float* __restrict__ xpw, const float* __restrict__ dtw,
    const float* __restrict__ opw, const float* __restrict__ alog,
    __hip_bfloat16* __restrict__ xbf, __hip_bfloat16* __restrict__ wbf,
    __hip_bfloat16* __restrict__ xpwbf, __hip_bfloat16* __restrict__ dtwbf,
    __hip_bfloat16* __restrict__ owbf, float* __restrict__ Aneg) {
  const int i = (blockIdx.x * 256 + threadIdx.x) * 8;
  const int n0 = MROWS * D_MODEL;               // x
  const int n1 = n0 + 2 * D_INNER * D_MODEL;    // in_proj
  const int n2 = n1 + 96 * D_INNER;             // x_proj
  const int n3 = n2 + D_INNER * DT_RANK;        // dt_proj
  const int n4 = n3 + D_MODEL * D_INNER;        // out_proj
  const int n5 = n4 + D_INNER * NSTATE;         // A_log
  const float* src; __hip_bfloat16* dst; int j;
  if (i < n0)      { src = x;    dst = xbf;   j = i; }
  else if (i < n1) { src = ipw;  dst = wbf;   j = i - n0; }
  else if (i < n2) { src = xpw;  dst = xpwbf; j = i - n1; }
  else if (i < n3) { src = dtw;  dst = dtwbf; j = i - n2; }
  else if (i < n4) { src = opw;  dst = owbf;  j = i - n3; }
  else if (i < n5) {
    int j2 = i - n4;
    float4 a = *(const float4*)(alog + j2);
    float4 b = *(const float4*)(alog + j2 + 4);
    float4 oa = {-expf(a.x), -expf(a.y), -expf(a.z), -expf(a.w)};
    float4 ob = {-expf(b.x), -expf(b.y), -expf(b.z), -expf(b.w)};
    *(float4*)(Aneg + j2) = oa;
    *(float4*)(Aneg + j2 + 4) = ob;
    return;
  } else return;
  float4 a = *(const float4*)(src + j);
  float4 b = *(const float4*)(src + j + 4);
  union { s16x8 v; unsigned short u[8]; } o;
  o.u[0] = f2bf(a.x); o.u[1] = f2bf(a.y); o.u[2] = f2bf(a.z); o.u[3] = f2bf(a.w);
  o.u[4] = f2bf(b.x); o.u[5] = f2bf(b.y); o.u[6] = f2bf(b.z); o.u[7] = f2bf(b.w);
  *(s16x8*)(dst + j) = o.v;
}

// ---------- m97-structure bf16 MFMA GEMM: C[M,N] = A[M,K] * Bw[N,K]^T ----------
// 128x128 tile, BK=32, global_load_lds width=16 into linear LDS, 4 waves 2x2,
// each wave 64x64 = 4x4 frags of 16x16x32.
// MODE 0: GEMM1 (in_proj): col<2048 -> xs fp32 ; col>=2048 -> silu -> zsil bf16
// MODE 1: GEMM2 (x_proj, split-K): atomicAdd fp32 into xdbl[M][96]
// MODE 2: GEMM3 (dt_proj): +bias, softplus -> dt fp32
// MODE 3: GEMM4 (out_proj): plain fp32 store
template<int MODE>
__global__ __launch_bounds__(256)
void gemm_bt(const __hip_bfloat16* __restrict__ A,
             const __hip_bfloat16* __restrict__ Bw,
             int M, int N, int K, int kchunk,
             float* __restrict__ e0,
             __hip_bfloat16* __restrict__ eb0,
             const float* __restrict__ bias) {
  __shared__ unsigned short As[128 * 32];  // linear: row*32+col (gl_lds constraint)
  __shared__ unsigned short Bs[128 * 32];
  const int m0 = blockIdx.x * 128;
  const int n0 = blockIdx.y * 128;
  const int kb = blockIdx.z * kchunk;
  const int ke = kb + kchunk;
  const int tid = threadIdx.x;
  const int lane = tid & 63;
  const int wave = tid >> 6;
  const int wr = wave >> 1, wc = wave & 1;
  const int lrow = lane & 15;
  const int kh = lane >> 4;        // frag k-half: kh*8
  const int srow = lane >> 2;      // staging: 0..15
  const int sc8 = (lane & 3) * 8;  // staging col (elements)

  f32x4 acc[4][4] = {};

  for (int k0 = kb; k0 < ke; k0 += 32) {
#pragma unroll
    for (int i = 0; i < 2; ++i) {
      const int row = wave * 32 + i * 16 + srow;
      // A tile
      gl_lds16(A + (size_t)(m0 + row) * K + k0 + sc8,
               As + wave * 1024 + i * 512);
      // B tile (clamp rows >= N; cols >= N are never stored)
      int brow = n0 + row; if (brow >= N) brow = N - 1;
      gl_lds16(Bw + (size_t)brow * K + k0 + sc8,
               Bs + wave * 1024 + i * 512);
    }
    __syncthreads();
    s16x8 af[4], bfr[4];
#pragma unroll
    for (int f = 0; f < 4; ++f)
      af[f] = *(const s16x8*)(As + (wr * 64 + f * 16 + lrow) * 32 + kh * 8);
#pragma unroll
    for (int g = 0; g < 4; ++g)
      bfr[g] = *(const s16x8*)(Bs + (wc * 64 + g * 16 + lrow) * 32 + kh * 8);
#pragma unroll
    for (int f = 0; f < 4; ++f)
#pragma unroll
      for (int g = 0; g < 4; ++g)
        acc[f][g] = __builtin_amdgcn_mfma_f32_16x16x32_bf16(af[f], bfr[g], acc[f][g], 0, 0, 0);
    __syncthreads();
  }

  // epilogue: lane holds D[row=(lane>>4)*4+j][col=lane&15] per frag (m89-verified)
#pragma unroll
  for (int f = 0; f < 4; ++f) {
    const int rbase = m0 + wr * 64 + f * 16 + (lane >> 4) * 4;
#pragma unroll
    for (int g = 0; g < 4; ++g) {
      const int col = n0 + wc * 64 + g * 16 + (lane & 15);
#pragma unroll
      for (int j = 0; j < 4; ++j) {
        float v = acc[f][g][j];
        const int r = rbase + j;
        if (MODE == 0) {
          if (col < D_INNER) e0[(size_t)r * D_INNER + col] = v;
          else {
            float s = v * fsigmoid(v);
            eb0[(size_t)r * D_INNER + (col - D_INNER)] = __float2bfloat16(s);
          }
        } else if (MODE == 1) {
          if (col < 96) atomicAdd(&e0[(size_t)r * 96 + col], v);
        } else if (MODE == 2) {
          float t = v + bias[col];
          float sp = (t > 20.f) ? t : __logf(1.f + __expf(t));
          e0[(size_t)r * D_INNER + col] = sp;
        } else {
          e0[(size_t)r * D_MODEL + col] = v;
        }
      }
    }
  }
}

// ---------- split xdbl -> dt_r (bf16) + B/C (fp32) ----------
__global__ __launch_bounds__(256)
void xdbl_finish(const float* __restrict__ xdbl, __hip_bfloat16* __restrict__ dtrbf,
                 float* __restrict__ bc) {
  int i = blockIdx.x * 256 + threadIdx.x;  // 4096*96
  int r = i / 96, c = i - r * 96;
  float v = xdbl[i];
  if (c < DT_RANK) dtrbf[r * DT_RANK + c] = __float2bfloat16(v);
  else bc[r * 32 + (c - DT_RANK)] = v;
}

// ---------- depthwise causal conv (k=4) + bias + silu, 4 channels/thread ----------
__global__ __launch_bounds__(256)
void conv_silu(const float* __restrict__ xs, const float* __restrict__ cw,
               const float* __restrict__ cb, float* __restrict__ xsc,
               __hip_bfloat16* __restrict__ xscbf) {
  const int g = blockIdx.x * 256 + threadIdx.x;  // 8388608/4 threads
  const int idx = g * 4;
  const int d = idx & (D_INNER - 1);
  const int l = (idx >> 11) & (SEQ - 1);
  const float* p = xs + (size_t)idx;
  const float4 z4 = {0.f, 0.f, 0.f, 0.f};
  float4 xm3 = (l >= 3) ? *(const float4*)(p - 3 * D_INNER) : z4;
  float4 xm2 = (l >= 2) ? *(const float4*)(p - 2 * D_INNER) : z4;
  float4 xm1 = (l >= 1) ? *(const float4*)(p - 1 * D_INNER) : z4;
  float4 x0 = *(const float4*)(p);
  const float4* cwv = (const float4*)(cw + d * 4);
  float4 cb4 = *(const float4*)(cb + d);
  float4 out;
  {
    float4 q = cwv[0];
    out.x = cb4.x + q.x * xm3.x + q.y * xm2.x + q.z * xm1.x + q.w * x0.x;
  }
  {
    float4 q = cwv[1];
    out.y = cb4.y + q.x * xm3.y + q.y * xm2.y + q.z * xm1.y + q.w * x0.y;
  }
  {
    float4 q = cwv[2];
    out.z = cb4.z + q.x * xm3.z + q.y * xm2.z + q.z * xm1.z + q.w * x0.z;
  }
  {
    float4 q = cwv[3];
    out.w = cb4.w + q.x * xm3.w + q.y * xm2.w + q.z * xm1.w + q.w * x0.w;
  }
  out.x *= fsigmoid(out.x); out.y *= fsigmoid(out.y);
  out.z *= fsigmoid(out.z); out.w *= fsigmoid(out.w);
  *(float4*)(xsc + idx) = out;
  u16x4 ob = {f2bf(out.x), f2bf(out.y), f2bf(out.z), f2bf(out.w)};
  *(u16x4*)((unsigned short*)xscbf + idx) = ob;
}

// ---------- scan pass 1: per-chunk final state + decay product (h0=0) ----------
__global__ __launch_bounds__(256)
void scan_pass1(const float* __restrict__ dt, const float* __restrict__ xsc,
                const float* __restrict__ bc, const float* __restrict__ Aneg,
                float* __restrict__ hfin, float* __restrict__ Pbuf) {
  const int b = blockIdx.z, c = blockIdx.y;
  const int d = blockIdx.x * 256 + threadIdx.x;
  __shared__ float BC[CLEN][32];
  const size_t mrow0 = (size_t)b * SEQ + (size_t)c * CLEN;
  for (int t = threadIdx.x; t < CLEN * 32; t += 256) {
    int i = t >> 5, col = t & 31;
    BC[i][col] = bc[(mrow0 + i) * 32 + col];
  }
  __syncthreads();
  float Ar[16];
#pragma unroll
  for (int n = 0; n < 16; ++n) Ar[n] = Aneg[d * 16 + n];
  float h[16], P[16];
#pragma unroll
  for (int n = 0; n < 16; ++n) { h[n] = 0.f; P[n] = 1.f; }
  size_t base = mrow0 * D_INNER + d;
  for (int l = 0; l < CLEN; ++l) {
    float dtv = dt[base + (size_t)l * D_INNER];
    float u = dtv * xsc[base + (size_t)l * D_INNER];
#pragma unroll
    for (int n = 0; n < 16; ++n) {
      float a = __expf(dtv * Ar[n]);
      h[n] = h[n] * a + u * BC[l][n];
      P[n] *= a;
    }
  }
  size_t o = (((size_t)b * NC + c) * D_INNER + d) * 16;
#pragma unroll
  for (int n = 0; n < 16; ++n) { hfin[o + n] = h[n]; Pbuf[o + n] = P[n]; }
}

// ---------- scan pass 2: cross-chunk combine; hfin becomes h_init per chunk ----------
__global__ __launch_bounds__(256)
void scan_pass2(float* __restrict__ hfin, const float* __restrict__ Pbuf) {
  int idx = blockIdx.x * 256 + threadIdx.x;  // B*D_INNER*16 = 65536
  int b = idx >> 15;
  int dn = idx & 32767;
  float h0 = 0.f;
  for (int c = 0; c < NC; ++c) {
    size_t o = ((size_t)b * NC + c) * 32768 + dn;
    float hf = hfin[o], p = Pbuf[o];
    hfin[o] = h0;
    h0 = hf + p * h0;
  }
}

// ---------- scan pass 3: re-run chunk from h_init, emit y=(scan+xs*D)*silu(z) bf16 ----------
__global__ __launch_bounds__(256)
void scan_pass3(const float* __restrict__ dt, const float* __restrict__ xsc,
                const float* __restrict__ bc, const float* __restrict__ Aneg,
                const float* __restrict__ hinit, const float* __restrict__ Dv,
                const __hip_bfloat16* __restrict__ zsil,
                __hip_bfloat16* __restrict__ ybf) {
  const int b = blockIdx.z, c = blockIdx.y;
  const int d = blockIdx.x * 256 + threadIdx.x;
  __shared__ float BC[CLEN][32];
  const size_t mrow0 = (size_t)b * SEQ + (size_t)c * CLEN;
  for (int t = threadIdx.x; t < CLEN * 32; t += 256) {
    int i = t >> 5, col = t & 31;
    BC[i][col] = bc[(mrow0 + i) * 32 + col];
  }
  __syncthreads();
  float Ar[16];
#pragma unroll
  for (int n = 0; n < 16; ++n) Ar[n] = Aneg[d * 16 + n];
  float h[16];
  size_t o = (((size_t)b * NC + c) * D_INNER + d) * 16;
#pragma unroll
  for (int n = 0; n < 16; ++n) h[n] = hinit[o + n];
  const float dval = Dv[d];
  size_t base = mrow0 * D_INNER + d;
  for (int l = 0; l < CLEN; ++l) {
    float dtv = dt[base + (size_t)l * D_INNER];
    float xv = xsc[base + (size_t)l * D_INNER];
    float u = dtv * xv;
    float y = 0.f;
#pragma unroll
    for (int n = 0; n < 16; ++n) {
      float a = __expf(dtv * Ar[n]);
      h[n] = h[n] * a + u * BC[l][n];
      y += h[n] * BC[l][16 + n];
    }
    float yo = y + xv * dval;
    float zg = __bfloat162float(zsil[base + (size_t)l * D_INNER]);
    ybf[base + (size_t)l * D_INNER] = __float2bfloat16(yo * zg);
  }
}

extern "C" void kernel_launch(void* const* d_in, const int* in_sizes, int n_in,
                              void* d_out, int out_size, void* d_ws, size_t ws_size,
                              hipStream_t stream) {
  const float* x    = (const float*)d_in[0];
  const float* ipw  = (const float*)d_in[1];
  const float* cw   = (const float*)d_in[2];
  const float* cb   = (const float*)d_in[3];
  const float* xpw  = (const float*)d_in[4];
  const float* dtw  = (const float*)d_in[5];
  const float* dtb  = (const float*)d_in[6];
  const float* alog = (const float*)d_in[7];
  const float* Dv   = (const float*)d_in[8];
  const float* opw  = (const float*)d_in[9];
  float* out = (float*)d_out;

  char* w = (char*)d_ws;
  // layout (bytes); ybf aliases xbf+wbf (dead after GEMM1); dt aliases xs; xdbl aliases Pbuf
  __hip_bfloat16* xbf   = (__hip_bfloat16*)(w + 0);          //  8,388,608
  __hip_bfloat16* wbf   = (__hip_bfloat16*)(w + 8388608);    //  8,388,608
  __hip_bfloat16* ybf   = (__hip_bfloat16*)(w + 0);          // 16,777,216 (alias)
  __hip_bfloat16* owbf  = (__hip_bfloat16*)(w + 16777216);   //  4,194,304
  __hip_bfloat16* xpwbf = (__hip_bfloat16*)(w + 20971520);   //    393,216
  __hip_bfloat16* dtwbf = (__hip_bfloat16*)(w + 21364736);   //    262,144
  float* Aneg           = (float*)(w + 21626880);            //    131,072
  float* xs             = (float*)(w + 21757952);            // 33,554,432
  float* dtbuf          = (float*)(w + 21757952);            // (alias of xs)
  __hip_bfloat16* zsil  = (__hip_bfloat16*)(w + 55312384);   // 16,777,216
  float* xsc            = (float*)(w + 72089600);            // 33,554,432
  __hip_bfloat16* xscbf = (__hip_bfloat16*)(w + 105644032);  // 16,777,216
  __hip_bfloat16* dtrbf = (__hip_bfloat16*)(w + 122421248);  //    524,288
  float* bc             = (float*)(w + 122945536);           //    524,288
  float* hfin           = (float*)(w + 123469824);           //  8,388,608
  float* Pbuf           = (float*)(w + 131858432);           //  8,388,608
  float* xdbl           = (float*)(w + 131858432);           //  1,572,864 (alias of Pbuf; dead before scans)
  // total: 140,247,040 bytes

  // 1. convert inputs to bf16 (+ A = -exp(A_log))
  {
    const int total = MROWS * D_MODEL + 2 * D_INNER * D_MODEL + 96 * D_INNER +
                      D_INNER * DT_RANK + D_MODEL * D_INNER + D_INNER * NSTATE;
    setup_convert<<<total / (256 * 8), 256, 0, stream>>>(
        x, ipw, xpw, dtw, opw, alog, xbf, wbf, xpwbf, dtwbf, owbf, Aneg);
  }
  // 2. GEMM1: xz = x @ in_proj^T  -> xs fp32, silu(z) bf16
  gemm_bt<0><<<dim3(32, 32), 256, 0, stream>>>(xbf, wbf, MROWS, 2 * D_INNER, D_MODEL,
                                               D_MODEL, xs, zsil, nullptr);
  // 3. depthwise conv + silu -> xsc fp32 + bf16
  conv_silu<<<(MROWS * D_INNER) / (256 * 4), 256, 0, stream>>>(xs, cw, cb, xsc, xscbf);
  // 4. GEMM2: x_dbl = xsc @ x_proj^T, split-K=16, atomicAdd -> xdbl fp32
  hipMemsetAsync(xdbl, 0, (size_t)MROWS * 96 * 4, stream);
  gemm_bt<1><<<dim3(32, 1, 16), 256, 0, stream>>>(xscbf, xpwbf, MROWS, 96, D_INNER,
                                                  D_INNER / 16, xdbl, nullptr, nullptr);
  xdbl_finish<<<(MROWS * 96) / 256, 256, 0, stream>>>(xdbl, dtrbf, bc);
  // 5. GEMM3: dt = softplus(dt_r @ dt_proj^T + b) -> fp32
  gemm_bt<2><<<dim3(32, 16), 256, 0, stream>>>(dtrbf, dtwbf, MROWS, D_INNER, DT_RANK,
                                               DT_RANK, dtbuf, nullptr, dtb);
  // 6-8. chunked selective scan
  scan_pass1<<<dim3(8, NC, 2), 256, 0, stream>>>(dtbuf, xsc, bc, Aneg, hfin, Pbuf);
  scan_pass2<<<256, 256, 0, stream>>>(hfin, Pbuf);
  scan_pass3<<<dim3(8, NC, 2), 256, 0, stream>>>(dtbuf, xsc, bc, Aneg, hfin, Dv, zsil, ybf);
  // 9. GEMM4: out = y @ out_proj^T
  gemm_bt<3><<<dim3(32, 8), 256, 0, stream>>>(ybf, owbf, MROWS, D_MODEL, D_INNER,
                                              D_INNER, out, nullptr, nullptr);
}